// Round 11
// baseline (41.552 us; speedup 1.0000x reference)
//
#include <hip/hip_runtime.h>
#include <hip/hip_bf16.h>
#include <stdint.h>

typedef unsigned short u16t;
typedef float f32x4 __attribute__((ext_vector_type(4)));
typedef short bf16x8 __attribute__((ext_vector_type(8)));

#define SDIM 224

__device__ __forceinline__ float lo16(uint32_t w) { union { uint32_t u; float f; } v; v.u = w << 16; return v.f; }
__device__ __forceinline__ float hi16(uint32_t w) { union { uint32_t u; float f; } v; v.u = w & 0xFFFF0000u; return v.f; }
__device__ __forceinline__ uint32_t f2bf(float f) {
    union { float f; uint32_t u; } v; v.f = f;
    return (v.u + 0x7FFFu + ((v.u >> 16) & 1u)) >> 16;
}

// ---------------------------------------------------------------------------
// Prep: pack GEMM B-operands, MFMA-frag order: buf[(kb*N+n)*8+j] = W[kb*8+j][n]
//  wtA: K=544 rows: [0,512) h2wA (k=i*64+h), [512,520) h2bA rows, [520,544) 0
//  wtB: K=416 rows: [0,384) h2wB, [384,390) h2bB, [390,404) act_w, [404,416) 0
//  wt2: K=64, N=64 (hb1_w | hw2_w);  wtM: K=64, N=32 (hw1_w)
// ---------------------------------------------------------------------------
__global__ void prep_wt_kernel(const float* __restrict__ h2wA, const float* __restrict__ h2wB,
                               const float* __restrict__ h2bA, const float* __restrict__ h2bB,
                               const float* __restrict__ actw,
                               const float* __restrict__ hb1w, const float* __restrict__ hw2w,
                               const float* __restrict__ hw1w,
                               u16t* __restrict__ wtA, u16t* __restrict__ wtB,
                               u16t* __restrict__ wt2, u16t* __restrict__ wtM)
{
    const int t0 = blockIdx.x * 256 + threadIdx.x, stride = gridDim.x * 256;
    for (int e = t0; e < 34816; e += stride) {           // 68 kb * 64 n * 8 j
        int j = e & 7, n = (e >> 3) & 63, kb = e >> 9;
        int k = kb * 8 + j;
        float v = 0.f;
        if (k < 512)      { int h = k & 63, i = k >> 6; v = h2wA[h * 512 + i * 64 + n]; }
        else if (k < 520) v = h2bA[(k - 512) * 64 + n];
        wtA[e] = (u16t)f2bf(v);
    }
    for (int e = t0; e < 26624; e += stride) {           // 52 kb * 64 n * 8 j
        int j = e & 7, n = (e >> 3) & 63, kb = e >> 9;
        int k = kb * 8 + j;
        float v = 0.f;
        if (k < 384)      { int h = k & 63, i = k >> 6; v = h2wB[h * 384 + i * 64 + n]; }
        else if (k < 390) v = h2bB[(k - 384) * 64 + n];
        else if (k < 404) v = actw[(k - 390) * 64 + n];
        wtB[e] = (u16t)f2bf(v);
    }
    for (int e = t0; e < 4096; e += stride) {
        int j = e & 7, n = (e >> 3) & 63, kb = e >> 9;
        int k = kb * 8 + j;
        float v = (n < 32) ? hb1w[k * 32 + n] : hw2w[k * 32 + (n - 32)];
        wt2[e] = (u16t)f2bf(v);
    }
    for (int e = t0; e < 2048; e += stride) {
        int j = e & 7, n = (e >> 3) & 31, kb = e >> 8;
        wtM[e] = (u16t)f2bf(hw1w[(kb * 8 + j) * 32 + n]);
    }
}

// ---------------------------------------------------------------------------
// stage1: psum[s][k=i*64+h] (bf16) for 4 wave-private samples. lane = h.
// ---------------------------------------------------------------------------
template<int DIN, int KP, int FOFF>
__device__ __forceinline__ void stage1(const u16t* __restrict__ xb, u16t* __restrict__ ps_base,
                                       const float* __restrict__ s_h1w, float b1r, int lane)
{
    float w1r[DIN];
#pragma unroll
    for (int i = 0; i < DIN; ++i) w1r[i] = s_h1w[i * 64 + lane];
#pragma unroll 1
    for (int s = 0; s < 4; ++s) {
        const u16t* xr = xb + s * SDIM + FOFF;
        float ps[DIN];
#pragma unroll
        for (int i = 0; i < DIN; ++i) ps[i] = 0.f;
#pragma unroll
        for (int a = 0; a < 8; ++a) {
            float x[DIN];
            if constexpr (DIN == 8) {
                uint4 v = *(const uint4*)(xr + a * 8);
                x[0] = lo16(v.x); x[1] = hi16(v.x); x[2] = lo16(v.y); x[3] = hi16(v.y);
                x[4] = lo16(v.z); x[5] = hi16(v.z); x[6] = lo16(v.w); x[7] = hi16(v.w);
            } else {
                uint32_t w0 = *(const uint32_t*)(xr + a * 6);
                uint32_t w1 = *(const uint32_t*)(xr + a * 6 + 2);
                uint32_t w2 = *(const uint32_t*)(xr + a * 6 + 4);
                x[0] = lo16(w0); x[1] = hi16(w0); x[2] = lo16(w1);
                x[3] = hi16(w1); x[4] = lo16(w2); x[5] = hi16(w2);
            }
            float hacc = b1r;
#pragma unroll
            for (int i = 0; i < DIN; ++i) hacc += x[i] * w1r[i];
            hacc = fmaxf(hacc, 0.f);
#pragma unroll
            for (int i = 0; i < DIN; ++i) ps[i] += hacc * x[i];
        }
#pragma unroll
        for (int i = 0; i < DIN; ++i) ps_base[s * KP + i * 64 + lane] = (u16t)f2bf(ps[i]);
    }
}

// ---------------------------------------------------------------------------
// Fused mixer, wave-private: each wave owns 4 samples end-to-end.
// One __syncthreads total (after shared weight staging). M=4 MFMA tiles with
// row-clamped A-fragments (every lane ends holding all 4 samples' results).
// ---------------------------------------------------------------------------
__global__ __launch_bounds__(256, 4)
void fused_mixer(const float* __restrict__ qvals, const float* __restrict__ states,
                 const float* __restrict__ hs,
                 const float* __restrict__ al_h1w, const float* __restrict__ al_h1b,
                 const float* __restrict__ en_h1w, const float* __restrict__ en_h1b,
                 const float* __restrict__ al_bias, const float* __restrict__ en_bias,
                 const float* __restrict__ act_b,
                 const float* __restrict__ hb1_b, const float* __restrict__ hw2_b,
                 const float* __restrict__ hw1_b, const float* __restrict__ hb2_w,
                 const float* __restrict__ hb2_b,
                 const u16t* __restrict__ wtA, const u16t* __restrict__ wtB,
                 const u16t* __restrict__ wt2, const u16t* __restrict__ wtM,
                 float* __restrict__ out)
{
    constexpr int KPA = 552, KPB = 424;
    __shared__ __align__(16) u16t s_xb[4][896];    // [wave][s*224+f] bf16 states
    __shared__ __align__(16) u16t s_un[4][2304];   // [wave] psumA/psumB then hs(32x72)
    __shared__ __align__(16) u16t s_sew[4][288];   // [wave][s*72+o] bf16 se
    __shared__ float s_b1w2[4][4][64];
    __shared__ float s_qw[4][32];
    __shared__ float s_b2w[4][4];
    __shared__ float s_h1wA[512], s_h1wB[384];
    __shared__ float s_h1bA[64], s_h1bB[64], s_bias3[64], s_hb2w[64];
    __shared__ float s_b1b[32], s_w2b[32], s_w1b[32];
    __shared__ float s_hb2bv;

    const int tid  = threadIdx.x;
    const int wave = tid >> 6;
    const int lane = tid & 63;
    const int lr = lane & 15, lg = lane >> 4;
    const int sbase = blockIdx.x * 16;
    const int wbase = sbase + wave * 4;            // this wave's first sample

    // ---- per-wave staging (own LDS region, no barrier needed) ----
    {
        const float* sb = states + (size_t)wbase * SDIM;
#pragma unroll
        for (int it = 0; it < 4; ++it) {
            int idx = it * 64 + lane;
            if (idx < 224) {
                int s = idx / 56, c = idx - s * 56;
                float4 v = *(const float4*)(sb + s * SDIM + c * 4);
                uint2 p;
                p.x = f2bf(v.x) | (f2bf(v.y) << 16);
                p.y = f2bf(v.z) | (f2bf(v.w) << 16);
                *(uint2*)&s_xb[wave][s * SDIM + c * 4] = p;
            }
        }
        if (lane < 32) s_qw[wave][lane] = qvals[(size_t)wbase * 8 + lane];
    }
    // ---- cooperative shared-weight staging ----
    for (int i = tid; i < 512; i += 256) s_h1wA[i] = al_h1w[i];
    for (int i = tid; i < 384; i += 256) s_h1wB[i] = en_h1w[i];
    if (tid < 64) {
        s_h1bA[tid] = al_h1b[tid]; s_h1bB[tid] = en_h1b[tid];
        s_bias3[tid] = al_bias[tid] + en_bias[tid] + act_b[tid];
        s_hb2w[tid] = hb2_w[tid];
    }
    if (tid >= 64 && tid < 96)   s_b1b[tid - 64] = hb1_b[tid - 64];
    if (tid >= 96 && tid < 128)  s_w2b[tid - 96] = hw2_b[tid - 96];
    if (tid >= 128 && tid < 160) s_w1b[tid - 128] = hw1_b[tid - 128];
    if (tid == 160) s_hb2bv = hb2_b[0];
    __syncthreads();                               // the ONLY barrier

    u16t* psA = s_un[wave];
    const u16t* xbw = s_xb[wave];

    // ---- phase A: stage1 + xsumA rows + zero pad ----
    stage1<8, KPA, 0>(xbw, psA, s_h1wA, s_h1bA[lane], lane);
    if (lane < 32) {                                // xsum rows k=512..519
        int s = lane >> 3, i = lane & 7;
        float t = 0.f;
#pragma unroll
        for (int a = 0; a < 8; ++a) t += lo16((uint32_t)xbw[s * SDIM + a * 8 + i]);
        psA[s * KPA + 512 + i] = (u16t)f2bf(t);
    }
    if (lane < 48) {                                // zero k=520..543
        int s = lane / 12, kp = lane - s * 12;
        *(uint32_t*)&psA[s * KPA + 520 + kp * 2] = 0u;
    }

    // ---- phase A MFMA: M=4(clamped), N=64 (4 n-tiles), K=544 ----
    f32x4 accA[4] = {{0.f,0.f,0.f,0.f},{0.f,0.f,0.f,0.f},{0.f,0.f,0.f,0.f},{0.f,0.f,0.f,0.f}};
    {
        const u16t* arow = psA + (lr & 3) * KPA + lg * 8;
        const bf16x8* wt8 = (const bf16x8*)wtA;
#pragma unroll 1
        for (int kk = 0; kk < 544; kk += 32) {
            bf16x8 av = *(const bf16x8*)(arow + kk);
            const int kb = (kk >> 3) + lg;
#pragma unroll
            for (int nt = 0; nt < 4; ++nt) {
                bf16x8 bv = wt8[kb * 64 + nt * 16 + lr];
                accA[nt] = __builtin_amdgcn_mfma_f32_16x16x32_bf16(av, bv, accA[nt], 0, 0, 0);
            }
        }
    }

    // ---- issue hs loads (hide under phase B) ----
    float4 hsr[8];
    {
        const float4* hsv = (const float4*)(hs + (size_t)wbase * 512);
#pragma unroll
        for (int i = 0; i < 8; ++i) hsr[i] = hsv[i * 64 + lane];
    }

    // ---- phase B: stage1 + xsumB/am rows + zero pad (psum region reused) ----
    stage1<6, KPB, 64>(xbw, psA, s_h1wB, s_h1bB[lane], lane);
    if (lane < 32 && (lane & 7) < 6) {              // xsum rows k=384..389
        int s = lane >> 3, i = lane & 7;
        float t = 0.f;
#pragma unroll
        for (int a = 0; a < 8; ++a) t += lo16((uint32_t)xbw[s * SDIM + 64 + a * 6 + i]);
        psA[s * KPB + 384 + i] = (u16t)f2bf(t);
    }
    if (lane < 56) {                                // raw action sums k=390..403
        int s = lane / 14, j = lane - s * 14;
        float t = 0.f;
#pragma unroll
        for (int a = 0; a < 8; ++a) t += lo16((uint32_t)xbw[s * SDIM + 112 + a * 14 + j]);
        psA[s * KPB + 390 + j] = (u16t)f2bf(t);
    }
    if (lane < 24) {                                // zero k=404..415
        int s = lane / 6, kp = lane - s * 6;
        *(uint32_t*)&psA[s * KPB + 404 + kp * 2] = 0u;
    }

    // ---- phase B MFMA: K=416 ----
    f32x4 accB[4] = {{0.f,0.f,0.f,0.f},{0.f,0.f,0.f,0.f},{0.f,0.f,0.f,0.f},{0.f,0.f,0.f,0.f}};
    {
        const u16t* arow = psA + (lr & 3) * KPB + lg * 8;
        const bf16x8* wt8 = (const bf16x8*)wtB;
#pragma unroll 1
        for (int kk = 0; kk < 416; kk += 32) {
            bf16x8 av = *(const bf16x8*)(arow + kk);
            const int kb = (kk >> 3) + lg;
#pragma unroll
            for (int nt = 0; nt < 4; ++nt) {
                bf16x8 bv = wt8[kb * 64 + nt * 16 + lr];
                accB[nt] = __builtin_amdgcn_mfma_f32_16x16x32_bf16(av, bv, accB[nt], 0, 0, 0);
            }
        }
    }

    // ---- hs regs -> LDS (psum region now dead) ----
    {
#pragma unroll
        for (int i = 0; i < 8; ++i) {
            const int idx = i * 64 + lane;
            const int row = idx >> 4, c4 = idx & 15;
            uint2 p;
            p.x = f2bf(hsr[i].x) | (f2bf(hsr[i].y) << 16);
            p.y = f2bf(hsr[i].z) | (f2bf(hsr[i].w) << 16);
            *(uint2*)&s_un[wave][row * 72 + c4 * 4] = p;
        }
    }

    // ---- se epilogue (all lanes hold all 4 samples; D row 4lg+j -> sample j) ----
    float sev[4][4];                                // [nt][j]
#pragma unroll
    for (int nt = 0; nt < 4; ++nt) {
        const int oo = nt * 16 + lr;
#pragma unroll
        for (int j = 0; j < 4; ++j) {
            float se = (accA[nt][j] + accB[nt][j]) * 0.125f + s_bias3[oo];
            sev[nt][j] = fmaxf(se, 0.f);
        }
    }
    if (lg == 0) {
#pragma unroll
        for (int nt = 0; nt < 4; ++nt)
#pragma unroll
            for (int j = 0; j < 4; ++j)
                s_sew[wave][j * 72 + nt * 16 + lr] = (u16t)f2bf(sev[nt][j]);
    }
    // ---- b2 from registers: p[j] = sum_o se[j][o]*hb2w[o] ----
    {
        float p0 = 0.f, p1 = 0.f, p2 = 0.f, p3 = 0.f;
#pragma unroll
        for (int nt = 0; nt < 4; ++nt) {
            const float w = s_hb2w[nt * 16 + lr];
            p0 += sev[nt][0] * w; p1 += sev[nt][1] * w;
            p2 += sev[nt][2] * w; p3 += sev[nt][3] * w;
        }
#pragma unroll
        for (int m2 = 1; m2 < 16; m2 <<= 1) {
            p0 += __shfl_xor(p0, m2); p1 += __shfl_xor(p1, m2);
            p2 += __shfl_xor(p2, m2); p3 += __shfl_xor(p3, m2);
        }
        if (lane == 0) {
            s_b2w[wave][0] = p0 + s_hb2bv; s_b2w[wave][1] = p1 + s_hb2bv;
            s_b2w[wave][2] = p2 + s_hb2bv; s_b2w[wave][3] = p3 + s_hb2bv;
        }
    }

    // ---- b1w2 MFMA: M=4(clamped), K=64, N=64 ----
    {
        f32x4 accW[4] = {{0.f,0.f,0.f,0.f},{0.f,0.f,0.f,0.f},{0.f,0.f,0.f,0.f},{0.f,0.f,0.f,0.f}};
        const u16t* serow = &s_sew[wave][(lr & 3) * 72 + lg * 8];
        const bf16x8* wt8 = (const bf16x8*)wt2;
#pragma unroll
        for (int ks = 0; ks < 2; ++ks) {
            bf16x8 av = *(const bf16x8*)(serow + ks * 32);
            const int kb = ks * 4 + lg;
#pragma unroll
            for (int nt = 0; nt < 4; ++nt) {
                bf16x8 bv = wt8[kb * 64 + nt * 16 + lr];
                accW[nt] = __builtin_amdgcn_mfma_f32_16x16x32_bf16(av, bv, accW[nt], 0, 0, 0);
            }
        }
        if (lg == 0) {
#pragma unroll
            for (int nt = 0; nt < 4; ++nt) {
                const int oo = nt * 16 + lr;
#pragma unroll
                for (int j = 0; j < 4; ++j) {
                    float v = accW[nt][j] + ((oo < 32) ? s_b1b[oo] : s_w2b[oo - 32]);
                    if (oo >= 32) v = fabsf(v);
                    s_b1w2[wave][j][oo] = v;
                }
            }
        }
    }

    // ---- mix: z MFMA over wave's 32 hs rows, softmax, ELU, final dot ----
    bf16x8 bfr[2][2];
    {
        const bf16x8* wtm8 = (const bf16x8*)wtM;
#pragma unroll
        for (int n = 0; n < 2; ++n)
#pragma unroll
            for (int ks = 0; ks < 2; ++ks)
                bfr[n][ks] = wtm8[(ks * 4 + lg) * 32 + n * 16 + lr];
    }
    const float zb0 = s_w1b[lr], zb1 = s_w1b[16 + lr];
    const u16t* hsl = s_un[wave];

#pragma unroll 1
    for (int t = 0; t < 2; ++t) {
        f32x4 d0 = {0.f,0.f,0.f,0.f}, d1 = {0.f,0.f,0.f,0.f};
#pragma unroll
        for (int ks = 0; ks < 2; ++ks) {
            bf16x8 av = *(const bf16x8*)&hsl[(t * 16 + lr) * 72 + ks * 32 + lg * 8];
            d0 = __builtin_amdgcn_mfma_f32_16x16x32_bf16(av, bfr[0][ks], d0, 0, 0, 0);
            d1 = __builtin_amdgcn_mfma_f32_16x16x32_bf16(av, bfr[1][ks], d1, 0, 0, 0);
        }
        const int sloc = t * 2 + (lg >> 1);
        float z0[4], z1[4];
#pragma unroll
        for (int j = 0; j < 4; ++j) { z0[j] = d0[j] + zb0; z1[j] = d1[j] + zb1; }
        float m0 = fmaxf(fmaxf(z0[0], z0[1]), fmaxf(z0[2], z0[3]));
        float m1 = fmaxf(fmaxf(z1[0], z1[1]), fmaxf(z1[2], z1[3]));
        m0 = fmaxf(m0, __shfl_xor(m0, 16));
        m1 = fmaxf(m1, __shfl_xor(m1, 16));
        float qa[4];
        {
            float4 qv = *(const float4*)&s_qw[wave][sloc * 8 + (lg & 1) * 4];
            qa[0] = qv.x; qa[1] = qv.y; qa[2] = qv.z; qa[3] = qv.w;
        }
        float s0 = 0.f, s1 = 0.f, hp0 = 0.f, hp1 = 0.f;
#pragma unroll
        for (int j = 0; j < 4; ++j) {
            float e0 = __expf(z0[j] - m0), e1 = __expf(z1[j] - m1);
            s0 += e0; s1 += e1;
            hp0 += qa[j] * e0; hp1 += qa[j] * e1;
        }
        s0  += __shfl_xor(s0, 16);  s1  += __shfl_xor(s1, 16);
        hp0 += __shfl_xor(hp0, 16); hp1 += __shfl_xor(hp1, 16);

        const float b1_0 = s_b1w2[wave][sloc][lr],      b1_1 = s_b1w2[wave][sloc][16 + lr];
        const float w2_0 = s_b1w2[wave][sloc][32 + lr], w2_1 = s_b1w2[wave][sloc][48 + lr];
        float h0 = hp0 / s0 + b1_0; h0 = (h0 > 0.f) ? h0 : (__expf(h0) - 1.f);
        float h1 = hp1 / s1 + b1_1; h1 = (h1 > 0.f) ? h1 : (__expf(h1) - 1.f);
        float yp = h0 * w2_0 + h1 * w2_1;
        yp += __shfl_xor(yp, 1); yp += __shfl_xor(yp, 2);
        yp += __shfl_xor(yp, 4); yp += __shfl_xor(yp, 8);
        if (lr == 0 && (lg & 1) == 0) out[wbase + sloc] = yp + s_b2w[wave][sloc];
    }
}

extern "C" void kernel_launch(void* const* d_in, const int* in_sizes, int n_in,
                              void* d_out, int out_size, void* d_ws, size_t ws_size,
                              hipStream_t stream) {
    const float* qvals   = (const float*)d_in[0];
    const float* states  = (const float*)d_in[1];
    const float* hstates = (const float*)d_in[2];
    const float* hw1_w   = (const float*)d_in[3];
    const float* hw1_b   = (const float*)d_in[4];
    const float* en_h1w  = (const float*)d_in[5];
    const float* en_h1b  = (const float*)d_in[6];
    const float* en_h2w  = (const float*)d_in[7];
    const float* en_h2b  = (const float*)d_in[8];
    const float* en_bias = (const float*)d_in[9];
    const float* al_h1w  = (const float*)d_in[10];
    const float* al_h1b  = (const float*)d_in[11];
    const float* al_h2w  = (const float*)d_in[12];
    const float* al_h2b  = (const float*)d_in[13];
    const float* al_bias = (const float*)d_in[14];
    const float* act_w   = (const float*)d_in[15];
    const float* act_b   = (const float*)d_in[16];
    const float* hb1_w   = (const float*)d_in[17];
    const float* hb1_b   = (const float*)d_in[18];
    const float* hw2_w   = (const float*)d_in[19];
    const float* hw2_b   = (const float*)d_in[20];
    const float* hb2_w   = (const float*)d_in[21];
    const float* hb2_b   = (const float*)d_in[22];

    // ws (u16): wtA@0 (34816) | wtB@34816 (26624) | wt2@61440 (4096) | wtM@65536 (2048)
    u16t* wtA = (u16t*)d_ws;
    u16t* wtB = wtA + 34816;
    u16t* wt2 = wtA + 61440;
    u16t* wtM = wtA + 65536;

    prep_wt_kernel<<<64, 256, 0, stream>>>(al_h2w, en_h2w, al_h2b, en_h2b, act_w,
                                           hb1_w, hw2_w, hw1_w, wtA, wtB, wt2, wtM);
    fused_mixer<<<1024, 256, 0, stream>>>(qvals, states, hstates,
                                          al_h1w, al_h1b, en_h1w, en_h1b,
                                          al_bias, en_bias, act_b,
                                          hb1_b, hw2_b, hw1_b, hb2_w, hb2_b,
                                          wtA, wtB, wt2, wtM, (float*)d_out);
}

// Round 12
// 38.168 us; speedup vs baseline: 1.0887x; 1.0887x over previous
//
#include <hip/hip_runtime.h>
#include <hip/hip_bf16.h>
#include <stdint.h>

typedef unsigned short u16t;
typedef float f32x4 __attribute__((ext_vector_type(4)));
typedef short bf16x8 __attribute__((ext_vector_type(8)));

#define SDIM 224

__device__ __forceinline__ float lo16(uint32_t w) { union { uint32_t u; float f; } v; v.u = w << 16; return v.f; }
__device__ __forceinline__ float hi16(uint32_t w) { union { uint32_t u; float f; } v; v.u = w & 0xFFFF0000u; return v.f; }
__device__ __forceinline__ uint32_t f2bf(float f) {
    union { float f; uint32_t u; } v; v.f = f;
    return (v.u + 0x7FFFu + ((v.u >> 16) & 1u)) >> 16;
}

// ---------------------------------------------------------------------------
// Prep: pack GEMM B-operands, MFMA-frag order: buf[(kb*N+n)*8+j] = W[kb*8+j][n]
//  wtA: K=544: [0,512) h2wA (k=i*64+h), [512,520) h2bA rows, [520,544) zero
//  wtB: K=416: [0,384) h2wB, [384,390) h2bB, [390,404) act_w, [404,416) zero
//  wt2: K=64, N=64 (hb1_w | hw2_w);  wtM: K=64, N=32 (hw1_w)
// ---------------------------------------------------------------------------
__global__ void prep_wt_kernel(const float* __restrict__ h2wA, const float* __restrict__ h2wB,
                               const float* __restrict__ h2bA, const float* __restrict__ h2bB,
                               const float* __restrict__ actw,
                               const float* __restrict__ hb1w, const float* __restrict__ hw2w,
                               const float* __restrict__ hw1w,
                               u16t* __restrict__ wtA, u16t* __restrict__ wtB,
                               u16t* __restrict__ wt2, u16t* __restrict__ wtM)
{
    const int t0 = blockIdx.x * 256 + threadIdx.x, stride = gridDim.x * 256;
    for (int e = t0; e < 34816; e += stride) {           // 68 kb * 64 n * 8 j
        int j = e & 7, n = (e >> 3) & 63, kb = e >> 9;
        int k = kb * 8 + j;
        float v = 0.f;
        if (k < 512)      { int h = k & 63, i = k >> 6; v = h2wA[h * 512 + i * 64 + n]; }
        else if (k < 520) v = h2bA[(k - 512) * 64 + n];
        wtA[e] = (u16t)f2bf(v);
    }
    for (int e = t0; e < 26624; e += stride) {           // 52 kb * 64 n * 8 j
        int j = e & 7, n = (e >> 3) & 63, kb = e >> 9;
        int k = kb * 8 + j;
        float v = 0.f;
        if (k < 384)      { int h = k & 63, i = k >> 6; v = h2wB[h * 384 + i * 64 + n]; }
        else if (k < 390) v = h2bB[(k - 384) * 64 + n];
        else if (k < 404) v = actw[(k - 390) * 64 + n];
        wtB[e] = (u16t)f2bf(v);
    }
    for (int e = t0; e < 4096; e += stride) {
        int j = e & 7, n = (e >> 3) & 63, kb = e >> 9;
        int k = kb * 8 + j;
        float v = (n < 32) ? hb1w[k * 32 + n] : hw2w[k * 32 + (n - 32)];
        wt2[e] = (u16t)f2bf(v);
    }
    for (int e = t0; e < 2048; e += stride) {
        int j = e & 7, n = (e >> 3) & 31, kb = e >> 8;
        wtM[e] = (u16t)f2bf(hw1w[(kb * 8 + j) * 32 + n]);
    }
}

// ---------------------------------------------------------------------------
// stage1: psum[s][k=i*64+h] (bf16), 2 samples per wave. lane = h.
// ---------------------------------------------------------------------------
template<int DIN, int KP, int FOFF>
__device__ __forceinline__ void stage1(const u16t (*xb)[SDIM], u16t* __restrict__ ps,
                                       const float* __restrict__ s_h1w, float b1r,
                                       int wave, int lane)
{
    float w1r[DIN];
#pragma unroll
    for (int i = 0; i < DIN; ++i) w1r[i] = s_h1w[i * 64 + lane];
#pragma unroll 1
    for (int ss = 0; ss < 2; ++ss) {
        const int s = wave * 2 + ss;
        const u16t* xr = &xb[s][FOFF];
        float psv[DIN];
#pragma unroll
        for (int i = 0; i < DIN; ++i) psv[i] = 0.f;
#pragma unroll
        for (int a = 0; a < 8; ++a) {
            float x[DIN];
            if constexpr (DIN == 8) {
                uint4 v = *(const uint4*)(xr + a * 8);
                x[0] = lo16(v.x); x[1] = hi16(v.x); x[2] = lo16(v.y); x[3] = hi16(v.y);
                x[4] = lo16(v.z); x[5] = hi16(v.z); x[6] = lo16(v.w); x[7] = hi16(v.w);
            } else {
                uint32_t w0 = *(const uint32_t*)(xr + a * 6);
                uint32_t w1 = *(const uint32_t*)(xr + a * 6 + 2);
                uint32_t w2 = *(const uint32_t*)(xr + a * 6 + 4);
                x[0] = lo16(w0); x[1] = hi16(w0); x[2] = lo16(w1);
                x[3] = hi16(w1); x[4] = lo16(w2); x[5] = hi16(w2);
            }
            float hacc = b1r;
#pragma unroll
            for (int i = 0; i < DIN; ++i) hacc += x[i] * w1r[i];
            hacc = fmaxf(hacc, 0.f);
#pragma unroll
            for (int i = 0; i < DIN; ++i) psv[i] += hacc * x[i];
        }
#pragma unroll
        for (int i = 0; i < DIN; ++i) ps[s * KP + i * 64 + lane] = (u16t)f2bf(psv[i]);
    }
}

// ---------------------------------------------------------------------------
// Fused mixer: 8 samples/block, grid 2048, 256 thr, target 7 blocks/CU.
// Block-cooperative M=8 tiles (A-rows clamped lr&7), K-extended GEMMs.
// ---------------------------------------------------------------------------
__global__ __launch_bounds__(256, 7)
void fused_mixer(const float* __restrict__ qvals, const float* __restrict__ states,
                 const float* __restrict__ hs,
                 const float* __restrict__ al_h1w, const float* __restrict__ al_h1b,
                 const float* __restrict__ en_h1w, const float* __restrict__ en_h1b,
                 const float* __restrict__ al_bias, const float* __restrict__ en_bias,
                 const float* __restrict__ act_b,
                 const float* __restrict__ hb1_b, const float* __restrict__ hw2_b,
                 const float* __restrict__ hw1_b, const float* __restrict__ hb2_w,
                 const float* __restrict__ hb2_b,
                 const u16t* __restrict__ wtA, const u16t* __restrict__ wtB,
                 const u16t* __restrict__ wt2, const u16t* __restrict__ wtM,
                 float* __restrict__ out)
{
    constexpr int KPA = 552, KPB = 424;
    __shared__ __align__(16) char s_un[9216];      // psum (8*552*2=8832) | hs (64*72*2)
    __shared__ __align__(16) u16t s_xb[8][SDIM];   // 3584 B bf16 states
    __shared__ __align__(16) u16t s_se[8 * 72];    // 1152 B
    __shared__ float s_b1w2[8][64];                // 2048 B
    __shared__ float s_b2[8];
    __shared__ float s_q[64];
    __shared__ float s_h1wA[512], s_h1wB[384];
    __shared__ float s_h1bA[64], s_h1bB[64], s_bias3[64], s_hb2w[64];
    __shared__ float s_b1b[32], s_w2b[32], s_w1b[32];
    __shared__ float s_hb2bv;

    const int tid  = threadIdx.x;
    const int wave = tid >> 6;
    const int lane = tid & 63;
    const int lr = lane & 15, lg = lane >> 4;
    const int sbase = blockIdx.x * 8;
    const int o = wave * 16 + lr;                  // this thread's output column

    // ---- staging ----
    for (int i = tid; i < 8 * 28; i += 256) {      // states f32 -> bf16 LDS
        int s = i / 28, c = i - s * 28;
        const float4* sp = (const float4*)(states + (size_t)(sbase + s) * SDIM + c * 8);
        float4 v0 = sp[0], v1 = sp[1];
        uint4 p;
        p.x = f2bf(v0.x) | (f2bf(v0.y) << 16);
        p.y = f2bf(v0.z) | (f2bf(v0.w) << 16);
        p.z = f2bf(v1.x) | (f2bf(v1.y) << 16);
        p.w = f2bf(v1.z) | (f2bf(v1.w) << 16);
        *(uint4*)&s_xb[s][c * 8] = p;
    }
    for (int i = tid; i < 512; i += 256) s_h1wA[i] = al_h1w[i];
    for (int i = tid; i < 384; i += 256) s_h1wB[i] = en_h1w[i];
    if (tid < 64) {
        s_h1bA[tid] = al_h1b[tid]; s_h1bB[tid] = en_h1b[tid];
        s_bias3[tid] = al_bias[tid] + en_bias[tid] + act_b[tid];
        s_hb2w[tid] = hb2_w[tid];
        s_q[tid] = qvals[(size_t)sbase * 8 + tid];
    }
    if (tid >= 64 && tid < 96)   s_b1b[tid - 64] = hb1_b[tid - 64];
    if (tid >= 96 && tid < 128)  s_w2b[tid - 96] = hw2_b[tid - 96];
    if (tid >= 128 && tid < 160) s_w1b[tid - 128] = hw1_b[tid - 128];
    if (tid == 160) s_hb2bv = hb2_b[0];
    __syncthreads();                               // B0

    u16t* ps = (u16t*)s_un;

    // ---- phase A stage1 + xsumA rows + zero pad ----
    stage1<8, KPA, 0>(s_xb, ps, s_h1wA, s_h1bA[lane], wave, lane);
    if (tid < 64) {                                 // xsum rows k=512..519
        int s = tid >> 3, i = tid & 7;
        float t = 0.f;
#pragma unroll
        for (int a = 0; a < 8; ++a) t += lo16((uint32_t)s_xb[s][a * 8 + i]);
        ps[s * KPA + 512 + i] = (u16t)f2bf(t);
    } else if (tid < 160) {                         // zero rows 520..543 (8s x 12 u32)
        int idx = tid - 64;
        int s = idx / 12, kp = idx - s * 12;
        *(uint32_t*)&ps[s * KPA + 520 + kp * 2] = 0u;
    }
    __syncthreads();                               // B1

    // ---- phase A MFMA: M=8 (A-rows lr&7), N=16/wave, K=544 ----
    f32x4 accA = {0.f, 0.f, 0.f, 0.f};
    {
        const u16t* arow = ps + (lr & 7) * KPA + lg * 8;
        const bf16x8* wt8 = (const bf16x8*)wtA;
#pragma unroll 4
        for (int kk = 0; kk < 544; kk += 32) {
            bf16x8 av = *(const bf16x8*)(arow + kk);
            bf16x8 bv = wt8[((kk >> 3) + lg) * 64 + o];
            accA = __builtin_amdgcn_mfma_f32_16x16x32_bf16(av, bv, accA, 0, 0, 0);
        }
    }
    __syncthreads();                               // B2 (psum free)

    // ---- issue hs loads (consumed after B4) ----
    float4 hsr[4];
    {
        const float4* hsv = (const float4*)(hs + (size_t)sbase * 512);
#pragma unroll
        for (int i = 0; i < 4; ++i) hsr[i] = hsv[i * 256 + tid];
    }

    // ---- phase B stage1 + xsumB/actsum rows + zero pad ----
    stage1<6, KPB, 64>(s_xb, ps, s_h1wB, s_h1bB[lane], wave, lane);
    if (tid < 48) {                                 // xsumB rows k=384..389
        int s = tid / 6, i = tid - s * 6;
        float t = 0.f;
#pragma unroll
        for (int a = 0; a < 8; ++a) t += lo16((uint32_t)s_xb[s][64 + a * 6 + i]);
        ps[s * KPB + 384 + i] = (u16t)f2bf(t);
    } else if (tid >= 64 && tid < 176) {            // raw action sums k=390..403
        int idx = tid - 64;
        int s = idx / 14, j = idx - s * 14;
        float t = 0.f;
#pragma unroll
        for (int a = 0; a < 8; ++a) t += lo16((uint32_t)s_xb[s][112 + a * 14 + j]);
        ps[s * KPB + 390 + j] = (u16t)f2bf(t);
    } else if (tid >= 192 && tid < 240) {           // zero rows 404..415 (8s x 6 u32)
        int idx = tid - 192;
        int s = idx / 6, kp = idx - s * 6;
        *(uint32_t*)&ps[s * KPB + 404 + kp * 2] = 0u;
    }
    __syncthreads();                               // B3

    // ---- phase B MFMA: K=416; then se epilogue ----
    {
        f32x4 accB = {0.f, 0.f, 0.f, 0.f};
        const u16t* arow = ps + (lr & 7) * KPB + lg * 8;
        const bf16x8* wt8 = (const bf16x8*)wtB;
#pragma unroll 4
        for (int kk = 0; kk < 416; kk += 32) {
            bf16x8 av = *(const bf16x8*)(arow + kk);
            bf16x8 bv = wt8[((kk >> 3) + lg) * 64 + o];
            accB = __builtin_amdgcn_mfma_f32_16x16x32_bf16(av, bv, accB, 0, 0, 0);
        }
        if (lg < 2) {                               // D rows 4*lg+j = samples 0..7
#pragma unroll
            for (int j = 0; j < 4; ++j) {
                const int row = lg * 4 + j;
                float se = (accA[j] + accB[j]) * 0.125f + s_bias3[o];
                s_se[row * 72 + o] = (u16t)f2bf(fmaxf(se, 0.f));
            }
        }
    }
    __syncthreads();                               // B4 (se ready, psum dead)

    // ---- hs regs -> LDS | b1w2 MFMA | b2 reduce ----
    u16t* s_hs = (u16t*)s_un;
    {
#pragma unroll
        for (int i = 0; i < 4; ++i) {
            const int idx = i * 256 + tid;
            const int row = idx >> 4, c4 = idx & 15;
            uint2 p;
            p.x = f2bf(hsr[i].x) | (f2bf(hsr[i].y) << 16);
            p.y = f2bf(hsr[i].z) | (f2bf(hsr[i].w) << 16);
            *(uint2*)&s_hs[row * 72 + c4 * 4] = p;
        }
    }
    {   // b1w2: M=8 (A-rows lr&7), K=64, N=16/wave
        f32x4 acc = {0.f, 0.f, 0.f, 0.f};
        const u16t* serow = &s_se[(lr & 7) * 72 + lg * 8];
        const bf16x8* wt8 = (const bf16x8*)wt2;
#pragma unroll
        for (int ks = 0; ks < 2; ++ks) {
            bf16x8 av = *(const bf16x8*)(serow + ks * 32);
            bf16x8 bv = wt8[(ks * 4 + lg) * 64 + o];
            acc = __builtin_amdgcn_mfma_f32_16x16x32_bf16(av, bv, acc, 0, 0, 0);
        }
        if (lg < 2) {
#pragma unroll
            for (int j = 0; j < 4; ++j) {
                const int row = lg * 4 + j;
                float v = acc[j] + ((o < 32) ? s_b1b[o] : s_w2b[o - 32]);
                if (o >= 32) v = fabsf(v);
                s_b1w2[row][o] = v;
            }
        }
    }
    {   // b2: (wave, lg&1) group reduces sample smp over all 64 cols
        const int smp = wave * 2 + (lg & 1);
        float p = 0.f;
#pragma unroll
        for (int c = 0; c < 4; ++c) {
            const int oo = c * 16 + lr;
            p += lo16((uint32_t)s_se[smp * 72 + oo]) * s_hb2w[oo];
        }
        p += __shfl_xor(p, 1); p += __shfl_xor(p, 2);
        p += __shfl_xor(p, 4); p += __shfl_xor(p, 8);
        if (lr == 0 && lg < 2) s_b2[smp] = p + s_hb2bv;
    }
    __syncthreads();                               // B5

    // ---- mix: one 16-row z-tile per wave (2 samples), softmax, ELU, dot ----
    bf16x8 bfr[2][2];
    {
        const bf16x8* wtm8 = (const bf16x8*)wtM;
#pragma unroll
        for (int n = 0; n < 2; ++n)
#pragma unroll
            for (int ks = 0; ks < 2; ++ks)
                bfr[n][ks] = wtm8[(ks * 4 + lg) * 32 + n * 16 + lr];
    }
    {
        const float zb0 = s_w1b[lr], zb1 = s_w1b[16 + lr];
        f32x4 d0 = {0.f,0.f,0.f,0.f}, d1 = {0.f,0.f,0.f,0.f};
#pragma unroll
        for (int ks = 0; ks < 2; ++ks) {
            bf16x8 av = *(const bf16x8*)&s_hs[(wave * 16 + lr) * 72 + ks * 32 + lg * 8];
            d0 = __builtin_amdgcn_mfma_f32_16x16x32_bf16(av, bfr[0][ks], d0, 0, 0, 0);
            d1 = __builtin_amdgcn_mfma_f32_16x16x32_bf16(av, bfr[1][ks], d1, 0, 0, 0);
        }
        const int sloc = wave * 2 + (lg >> 1);
        float z0[4], z1[4];
#pragma unroll
        for (int j = 0; j < 4; ++j) { z0[j] = d0[j] + zb0; z1[j] = d1[j] + zb1; }
        float m0 = fmaxf(fmaxf(z0[0], z0[1]), fmaxf(z0[2], z0[3]));
        float m1 = fmaxf(fmaxf(z1[0], z1[1]), fmaxf(z1[2], z1[3]));
        m0 = fmaxf(m0, __shfl_xor(m0, 16));
        m1 = fmaxf(m1, __shfl_xor(m1, 16));
        float qa[4];
        {
            float4 qv = *(const float4*)&s_q[sloc * 8 + (lg & 1) * 4];
            qa[0] = qv.x; qa[1] = qv.y; qa[2] = qv.z; qa[3] = qv.w;
        }
        float s0 = 0.f, s1 = 0.f, hp0 = 0.f, hp1 = 0.f;
#pragma unroll
        for (int j = 0; j < 4; ++j) {
            float e0 = __expf(z0[j] - m0), e1 = __expf(z1[j] - m1);
            s0 += e0; s1 += e1;
            hp0 += qa[j] * e0; hp1 += qa[j] * e1;
        }
        s0  += __shfl_xor(s0, 16);  s1  += __shfl_xor(s1, 16);
        hp0 += __shfl_xor(hp0, 16); hp1 += __shfl_xor(hp1, 16);

        const float b1_0 = s_b1w2[sloc][lr],      b1_1 = s_b1w2[sloc][16 + lr];
        const float w2_0 = s_b1w2[sloc][32 + lr], w2_1 = s_b1w2[sloc][48 + lr];
        float h0 = hp0 / s0 + b1_0; h0 = (h0 > 0.f) ? h0 : (__expf(h0) - 1.f);
        float h1 = hp1 / s1 + b1_1; h1 = (h1 > 0.f) ? h1 : (__expf(h1) - 1.f);
        float yp = h0 * w2_0 + h1 * w2_1;
        yp += __shfl_xor(yp, 1); yp += __shfl_xor(yp, 2);
        yp += __shfl_xor(yp, 4); yp += __shfl_xor(yp, 8);
        if (lr == 0 && (lg & 1) == 0) out[sbase + sloc] = yp + s_b2[sloc];
    }
}

extern "C" void kernel_launch(void* const* d_in, const int* in_sizes, int n_in,
                              void* d_out, int out_size, void* d_ws, size_t ws_size,
                              hipStream_t stream) {
    const float* qvals   = (const float*)d_in[0];
    const float* states  = (const float*)d_in[1];
    const float* hstates = (const float*)d_in[2];
    const float* hw1_w   = (const float*)d_in[3];
    const float* hw1_b   = (const float*)d_in[4];
    const float* en_h1w  = (const float*)d_in[5];
    const float* en_h1b  = (const float*)d_in[6];
    const float* en_h2w  = (const float*)d_in[7];
    const float* en_h2b  = (const float*)d_in[8];
    const float* en_bias = (const float*)d_in[9];
    const float* al_h1w  = (const float*)d_in[10];
    const float* al_h1b  = (const float*)d_in[11];
    const float* al_h2w  = (const float*)d_in[12];
    const float* al_h2b  = (const float*)d_in[13];
    const float* al_bias = (const float*)d_in[14];
    const float* act_w   = (const float*)d_in[15];
    const float* act_b   = (const float*)d_in[16];
    const float* hb1_w   = (const float*)d_in[17];
    const float* hb1_b   = (const float*)d_in[18];
    const float* hw2_w   = (const float*)d_in[19];
    const float* hw2_b   = (const float*)d_in[20];
    const float* hb2_w   = (const float*)d_in[21];
    const float* hb2_b   = (const float*)d_in[22];

    // ws (u16): wtA@0 (34816) | wtB@34816 (26624) | wt2@61440 (4096) | wtM@65536 (2048)
    u16t* wtA = (u16t*)d_ws;
    u16t* wtB = wtA + 34816;
    u16t* wt2 = wtA + 61440;
    u16t* wtM = wtA + 65536;

    prep_wt_kernel<<<64, 256, 0, stream>>>(al_h2w, en_h2w, al_h2b, en_h2b, act_w,
                                           hb1_w, hw2_w, hw1_w, wtA, wtB, wt2, wtM);
    fused_mixer<<<2048, 256, 0, stream>>>(qvals, states, hstates,
                                          al_h1w, al_h1b, en_h1w, en_h1b,
                                          al_bias, en_bias, act_b,
                                          hb1_b, hw2_b, hw1_b, hb2_w, hb2_b,
                                          wtA, wtB, wt2, wtM, (float*)d_out);
}

// Round 13
// 36.337 us; speedup vs baseline: 1.1435x; 1.0504x over previous
//
#include <hip/hip_runtime.h>
#include <hip/hip_bf16.h>
#include <stdint.h>

typedef unsigned short u16t;
typedef float f32x4 __attribute__((ext_vector_type(4)));
typedef short bf16x8 __attribute__((ext_vector_type(8)));

#define SDIM 224

__device__ __forceinline__ float lo16(uint32_t w) { union { uint32_t u; float f; } v; v.u = w << 16; return v.f; }
__device__ __forceinline__ float hi16(uint32_t w) { union { uint32_t u; float f; } v; v.u = w & 0xFFFF0000u; return v.f; }
__device__ __forceinline__ uint32_t f2bf(float f) {
    union { float f; uint32_t u; } v; v.f = f;
    return (v.u + 0x7FFFu + ((v.u >> 16) & 1u)) >> 16;
}

// ---------------------------------------------------------------------------
// Prep: one fused B-operand wtAB, K=960, MFMA-frag order
// buf[(kb*64+n)*8+j] = W[kb*8+j][n]:
//   k in [0,512): al_h2w (k=i*64+h) | [512,520): al_h2b rows | [520,544): 0
//   k-544 in [0,384): en_h2w | [384,390): en_h2b | [390,404): act_w | [404,416): 0
// wt2: K=64,N=64 (hb1_w|hw2_w); wtM: K=64,N=32 (hw1_w)
// ---------------------------------------------------------------------------
__global__ void prep_wt_kernel(const float* __restrict__ h2wA, const float* __restrict__ h2wB,
                               const float* __restrict__ h2bA, const float* __restrict__ h2bB,
                               const float* __restrict__ actw,
                               const float* __restrict__ hb1w, const float* __restrict__ hw2w,
                               const float* __restrict__ hw1w,
                               u16t* __restrict__ wtAB, u16t* __restrict__ wt2,
                               u16t* __restrict__ wtM)
{
    const int t0 = blockIdx.x * 256 + threadIdx.x, stride = gridDim.x * 256;
    for (int e = t0; e < 61440; e += stride) {           // 120 kb * 64 n * 8 j
        int j = e & 7, n = (e >> 3) & 63, kb = e >> 9;
        int k = kb * 8 + j;
        float v = 0.f;
        if (k < 512)      { int h = k & 63, i = k >> 6; v = h2wA[h * 512 + i * 64 + n]; }
        else if (k < 520) v = h2bA[(k - 512) * 64 + n];
        else if (k >= 544) {
            int k2 = k - 544;
            if (k2 < 384)      { int h = k2 & 63, i = k2 >> 6; v = h2wB[h * 384 + i * 64 + n]; }
            else if (k2 < 390) v = h2bB[(k2 - 384) * 64 + n];
            else if (k2 < 404) v = actw[(k2 - 390) * 64 + n];
        }
        wtAB[e] = (u16t)f2bf(v);
    }
    for (int e = t0; e < 4096; e += stride) {
        int j = e & 7, n = (e >> 3) & 63, kb = e >> 9;
        int k = kb * 8 + j;
        float v = (n < 32) ? hb1w[k * 32 + n] : hw2w[k * 32 + (n - 32)];
        wt2[e] = (u16t)f2bf(v);
    }
    for (int e = t0; e < 2048; e += stride) {
        int j = e & 7, n = (e >> 3) & 31, kb = e >> 8;
        wtM[e] = (u16t)f2bf(hw1w[(kb * 8 + j) * 32 + n]);
    }
}

// ---------------------------------------------------------------------------
// stage1: psum[s][k=i*64+h] (bf16), 2 samples per wave. lane = h.
// ---------------------------------------------------------------------------
template<int DIN, int KP, int FOFF>
__device__ __forceinline__ void stage1(const u16t (*xb)[SDIM], u16t* __restrict__ ps,
                                       const float* __restrict__ s_h1w, float b1r,
                                       int wave, int lane)
{
    float w1r[DIN];
#pragma unroll
    for (int i = 0; i < DIN; ++i) w1r[i] = s_h1w[i * 64 + lane];
#pragma unroll 1
    for (int ss = 0; ss < 2; ++ss) {
        const int s = wave * 2 + ss;
        const u16t* xr = &xb[s][FOFF];
        float psv[DIN];
#pragma unroll
        for (int i = 0; i < DIN; ++i) psv[i] = 0.f;
#pragma unroll
        for (int a = 0; a < 8; ++a) {
            float x[DIN];
            if constexpr (DIN == 8) {
                uint4 v = *(const uint4*)(xr + a * 8);
                x[0] = lo16(v.x); x[1] = hi16(v.x); x[2] = lo16(v.y); x[3] = hi16(v.y);
                x[4] = lo16(v.z); x[5] = hi16(v.z); x[6] = lo16(v.w); x[7] = hi16(v.w);
            } else {
                uint32_t w0 = *(const uint32_t*)(xr + a * 6);
                uint32_t w1 = *(const uint32_t*)(xr + a * 6 + 2);
                uint32_t w2 = *(const uint32_t*)(xr + a * 6 + 4);
                x[0] = lo16(w0); x[1] = hi16(w0); x[2] = lo16(w1);
                x[3] = hi16(w1); x[4] = lo16(w2); x[5] = hi16(w2);
            }
            float hacc = b1r;
#pragma unroll
            for (int i = 0; i < DIN; ++i) hacc += x[i] * w1r[i];
            hacc = fmaxf(hacc, 0.f);
#pragma unroll
            for (int i = 0; i < DIN; ++i) psv[i] += hacc * x[i];
        }
#pragma unroll
        for (int i = 0; i < DIN; ++i) ps[s * KP + i * 64 + lane] = (u16t)f2bf(psv[i]);
    }
}

// ---------------------------------------------------------------------------
// Fused mixer: 8 samples/block, grid 2048, 4 barriers, merged K=960 GEMM,
// z/softmax hoisted into phase 1 (overlaps stage1).
// ---------------------------------------------------------------------------
__global__ __launch_bounds__(256, 4)
void fused_mixer(const float* __restrict__ qvals, const float* __restrict__ states,
                 const float* __restrict__ hs,
                 const float* __restrict__ al_h1w, const float* __restrict__ al_h1b,
                 const float* __restrict__ en_h1w, const float* __restrict__ en_h1b,
                 const float* __restrict__ al_bias, const float* __restrict__ en_bias,
                 const float* __restrict__ act_b,
                 const float* __restrict__ hb1_b, const float* __restrict__ hw2_b,
                 const float* __restrict__ hw1_b, const float* __restrict__ hb2_w,
                 const float* __restrict__ hb2_b,
                 const u16t* __restrict__ wtAB, const u16t* __restrict__ wt2,
                 const u16t* __restrict__ wtM,
                 float* __restrict__ out)
{
    constexpr int KP = 968;                        // 960 + 8 pad (u16)
    __shared__ __align__(16) u16t s_ps[8 * KP];    // 15488 B
    __shared__ __align__(16) u16t s_hs[64 * 72];   // 9216 B
    __shared__ __align__(16) u16t s_xb[8][SDIM];   // 3584 B
    __shared__ __align__(16) u16t s_se[8 * 72];    // 1152 B
    __shared__ float s_b1w2[8][64];                // 2048 B
    __shared__ float s_b2[8];
    __shared__ float s_h1wA[512], s_h1wB[384];
    __shared__ float s_h1bA[64], s_h1bB[64], s_bias3[64], s_hb2w[64];
    __shared__ float s_b1b[32], s_w2b[32], s_w1b[32];
    __shared__ float s_hb2bv;

    const int tid  = threadIdx.x;
    const int wave = tid >> 6;
    const int lane = tid & 63;
    const int lr = lane & 15, lg = lane >> 4;
    const int sbase = blockIdx.x * 8;
    const int o = wave * 16 + lr;                  // this thread's output column

    // ---- B0 staging: xb, hs, weights ----
    for (int i = tid; i < 8 * 28; i += 256) {      // states f32 -> bf16 LDS
        int s = i / 28, c = i - s * 28;
        const float4* sp = (const float4*)(states + (size_t)(sbase + s) * SDIM + c * 8);
        float4 v0 = sp[0], v1 = sp[1];
        uint4 p;
        p.x = f2bf(v0.x) | (f2bf(v0.y) << 16);
        p.y = f2bf(v0.z) | (f2bf(v0.w) << 16);
        p.z = f2bf(v1.x) | (f2bf(v1.y) << 16);
        p.w = f2bf(v1.z) | (f2bf(v1.w) << 16);
        *(uint4*)&s_xb[s][c * 8] = p;
    }
    {
        const float4* hsv = (const float4*)(hs + (size_t)sbase * 512);
#pragma unroll
        for (int i = 0; i < 4; ++i) {
            const int idx = i * 256 + tid;
            float4 v = hsv[idx];
            const int row = idx >> 4, c4 = idx & 15;
            uint2 p;
            p.x = f2bf(v.x) | (f2bf(v.y) << 16);
            p.y = f2bf(v.z) | (f2bf(v.w) << 16);
            *(uint2*)&s_hs[row * 72 + c4 * 4] = p;
        }
    }
    for (int i = tid; i < 512; i += 256) s_h1wA[i] = al_h1w[i];
    for (int i = tid; i < 384; i += 256) s_h1wB[i] = en_h1w[i];
    if (tid < 64) {
        s_h1bA[tid] = al_h1b[tid]; s_h1bB[tid] = en_h1b[tid];
        s_bias3[tid] = al_bias[tid] + en_bias[tid] + act_b[tid];
        s_hb2w[tid] = hb2_w[tid];
    }
    if (tid >= 64 && tid < 96)   s_b1b[tid - 64] = hb1_b[tid - 64];
    if (tid >= 96 && tid < 128)  s_w2b[tid - 96] = hw2_b[tid - 96];
    if (tid >= 128 && tid < 160) s_w1b[tid - 128] = hw1_b[tid - 128];
    if (tid == 160) s_hb2bv = hb2_b[0];
    __syncthreads();                               // B0

    // ---- P1a: stage1 A then B into merged psum, + extension rows ----
    stage1<8, KP, 0>(s_xb, s_ps, s_h1wA, s_h1bA[lane], wave, lane);
    stage1<6, KP, 64>(s_xb, s_ps + 544, s_h1wB, s_h1bB[lane], wave, lane);
    if (tid < 64) {                                 // xsumA rows k=512..519
        int s = tid >> 3, i = tid & 7;
        float t = 0.f;
#pragma unroll
        for (int a = 0; a < 8; ++a) t += lo16((uint32_t)s_xb[s][a * 8 + i]);
        s_ps[s * KP + 512 + i] = (u16t)f2bf(t);
    } else if (tid < 112) {                         // xsumB rows k=928..933
        int idx = tid - 64;
        int s = idx / 6, i = idx - s * 6;
        float t = 0.f;
#pragma unroll
        for (int a = 0; a < 8; ++a) t += lo16((uint32_t)s_xb[s][64 + a * 6 + i]);
        s_ps[s * KP + 928 + i] = (u16t)f2bf(t);
    } else if (tid < 224) {                         // action sums k=934..947
        int idx = tid - 112;
        int s = idx / 14, j = idx - s * 14;
        float t = 0.f;
#pragma unroll
        for (int a = 0; a < 8; ++a) t += lo16((uint32_t)s_xb[s][112 + a * 14 + j]);
        s_ps[s * KP + 934 + j] = (u16t)f2bf(t);
    } else {                                        // zeros: k=520..543 and 948..959
        int idx = tid - 224;                        // 32 threads
        int s = idx >> 2, c = idx & 3;
#pragma unroll
        for (int u = 0; u < 3; ++u)
            *(uint32_t*)&s_ps[s * KP + 520 + c * 6 + u * 2] = 0u;
        if (c < 3)
            *(uint32_t*)&s_ps[s * KP + 948 + c * 4] = 0u;
        else
            *(uint32_t*)&s_ps[s * KP + 948 + 8 + 2] = 0u;   // last u32 (958,959)
    }

    // ---- P1b: z-MFMA + softmax + q-mix (independent of psum) ----
    float hp0, hp1, s0, s1;
    {
        bf16x8 bfr[2][2];
        const bf16x8* wtm8 = (const bf16x8*)wtM;
#pragma unroll
        for (int n = 0; n < 2; ++n)
#pragma unroll
            for (int ks = 0; ks < 2; ++ks)
                bfr[n][ks] = wtm8[(ks * 4 + lg) * 32 + n * 16 + lr];

        f32x4 d0 = {0.f,0.f,0.f,0.f}, d1 = {0.f,0.f,0.f,0.f};
#pragma unroll
        for (int ks = 0; ks < 2; ++ks) {
            bf16x8 av = *(const bf16x8*)&s_hs[(wave * 16 + lr) * 72 + ks * 32 + lg * 8];
            d0 = __builtin_amdgcn_mfma_f32_16x16x32_bf16(av, bfr[0][ks], d0, 0, 0, 0);
            d1 = __builtin_amdgcn_mfma_f32_16x16x32_bf16(av, bfr[1][ks], d1, 0, 0, 0);
        }
        const int sloc = wave * 2 + (lg >> 1);
        const float zb0 = s_w1b[lr], zb1 = s_w1b[16 + lr];
        float z0[4], z1[4];
#pragma unroll
        for (int j = 0; j < 4; ++j) { z0[j] = d0[j] + zb0; z1[j] = d1[j] + zb1; }
        float m0 = fmaxf(fmaxf(z0[0], z0[1]), fmaxf(z0[2], z0[3]));
        float m1 = fmaxf(fmaxf(z1[0], z1[1]), fmaxf(z1[2], z1[3]));
        m0 = fmaxf(m0, __shfl_xor(m0, 16));
        m1 = fmaxf(m1, __shfl_xor(m1, 16));
        float qa[4];
        {
            const float* qp = qvals + (size_t)(sbase + sloc) * 8 + (lg & 1) * 4;
            float4 qv = *(const float4*)qp;
            qa[0] = qv.x; qa[1] = qv.y; qa[2] = qv.z; qa[3] = qv.w;
        }
        s0 = 0.f; s1 = 0.f; hp0 = 0.f; hp1 = 0.f;
#pragma unroll
        for (int j = 0; j < 4; ++j) {
            float e0 = __expf(z0[j] - m0), e1 = __expf(z1[j] - m1);
            s0 += e0; s1 += e1;
            hp0 += qa[j] * e0; hp1 += qa[j] * e1;
        }
        s0  += __shfl_xor(s0, 16);  s1  += __shfl_xor(s1, 16);
        hp0 += __shfl_xor(hp0, 16); hp1 += __shfl_xor(hp1, 16);
    }
    __syncthreads();                               // B1

    // ---- P2: merged GEMM K=960, M=8 (A-rows lr&7), N=16/wave ----
    {
        f32x4 acc = {0.f, 0.f, 0.f, 0.f};
        const u16t* arow = s_ps + (lr & 7) * KP + lg * 8;
        const bf16x8* wt8 = (const bf16x8*)wtAB;
#pragma unroll 5
        for (int kk = 0; kk < 960; kk += 32) {
            bf16x8 av = *(const bf16x8*)(arow + kk);
            bf16x8 bv = wt8[((kk >> 3) + lg) * 64 + o];
            acc = __builtin_amdgcn_mfma_f32_16x16x32_bf16(av, bv, acc, 0, 0, 0);
        }
        if (lg < 2) {                               // rows 0..7 = samples
#pragma unroll
            for (int j = 0; j < 4; ++j) {
                const int row = lg * 4 + j;
                float se = acc[j] * 0.125f + s_bias3[o];
                s_se[row * 72 + o] = (u16t)f2bf(fmaxf(se, 0.f));
            }
        }
    }
    __syncthreads();                               // B2

    // ---- P3: b1w2 MFMA + b2 reduce ----
    {
        f32x4 acc = {0.f, 0.f, 0.f, 0.f};
        const u16t* serow = &s_se[(lr & 7) * 72 + lg * 8];
        const bf16x8* wt8 = (const bf16x8*)wt2;
#pragma unroll
        for (int ks = 0; ks < 2; ++ks) {
            bf16x8 av = *(const bf16x8*)(serow + ks * 32);
            bf16x8 bv = wt8[(ks * 4 + lg) * 64 + o];
            acc = __builtin_amdgcn_mfma_f32_16x16x32_bf16(av, bv, acc, 0, 0, 0);
        }
        if (lg < 2) {
#pragma unroll
            for (int j = 0; j < 4; ++j) {
                const int row = lg * 4 + j;
                float v = acc[j] + ((o < 32) ? s_b1b[o] : s_w2b[o - 32]);
                if (o >= 32) v = fabsf(v);
                s_b1w2[row][o] = v;
            }
        }
    }
    {
        const int smp = wave * 2 + (lg & 1);
        float p = 0.f;
#pragma unroll
        for (int c = 0; c < 4; ++c) {
            const int oo = c * 16 + lr;
            p += lo16((uint32_t)s_se[smp * 72 + oo]) * s_hb2w[oo];
        }
        p += __shfl_xor(p, 1); p += __shfl_xor(p, 2);
        p += __shfl_xor(p, 4); p += __shfl_xor(p, 8);
        if (lr == 0 && lg < 2) s_b2[smp] = p + s_hb2bv;
    }
    __syncthreads();                               // B3

    // ---- P4: ELU + final dot (z/softmax already in hp/s) ----
    {
        const int sloc = wave * 2 + (lg >> 1);
        const float b1_0 = s_b1w2[sloc][lr],      b1_1 = s_b1w2[sloc][16 + lr];
        const float w2_0 = s_b1w2[sloc][32 + lr], w2_1 = s_b1w2[sloc][48 + lr];
        float h0 = hp0 / s0 + b1_0; h0 = (h0 > 0.f) ? h0 : (__expf(h0) - 1.f);
        float h1 = hp1 / s1 + b1_1; h1 = (h1 > 0.f) ? h1 : (__expf(h1) - 1.f);
        float yp = h0 * w2_0 + h1 * w2_1;
        yp += __shfl_xor(yp, 1); yp += __shfl_xor(yp, 2);
        yp += __shfl_xor(yp, 4); yp += __shfl_xor(yp, 8);
        if (lr == 0 && (lg & 1) == 0) out[sbase + sloc] = yp + s_b2[sloc];
    }
}

extern "C" void kernel_launch(void* const* d_in, const int* in_sizes, int n_in,
                              void* d_out, int out_size, void* d_ws, size_t ws_size,
                              hipStream_t stream) {
    const float* qvals   = (const float*)d_in[0];
    const float* states  = (const float*)d_in[1];
    const float* hstates = (const float*)d_in[2];
    const float* hw1_w   = (const float*)d_in[3];
    const float* hw1_b   = (const float*)d_in[4];
    const float* en_h1w  = (const float*)d_in[5];
    const float* en_h1b  = (const float*)d_in[6];
    const float* en_h2w  = (const float*)d_in[7];
    const float* en_h2b  = (const float*)d_in[8];
    const float* en_bias = (const float*)d_in[9];
    const float* al_h1w  = (const float*)d_in[10];
    const float* al_h1b  = (const float*)d_in[11];
    const float* al_h2w  = (const float*)d_in[12];
    const float* al_h2b  = (const float*)d_in[13];
    const float* al_bias = (const float*)d_in[14];
    const float* act_w   = (const float*)d_in[15];
    const float* act_b   = (const float*)d_in[16];
    const float* hb1_w   = (const float*)d_in[17];
    const float* hb1_b   = (const float*)d_in[18];
    const float* hw2_w   = (const float*)d_in[19];
    const float* hw2_b   = (const float*)d_in[20];
    const float* hb2_w   = (const float*)d_in[21];
    const float* hb2_b   = (const float*)d_in[22];

    // ws (u16): wtAB@0 (61440) | wt2@61440 (4096) | wtM@65536 (2048)
    u16t* wtAB = (u16t*)d_ws;
    u16t* wt2  = wtAB + 61440;
    u16t* wtM  = wtAB + 65536;

    prep_wt_kernel<<<64, 256, 0, stream>>>(al_h2w, en_h2w, al_h2b, en_h2b, act_w,
                                           hb1_w, hw2_w, hw1_w, wtAB, wt2, wtM);
    fused_mixer<<<2048, 256, 0, stream>>>(qvals, states, hstates,
                                          al_h1w, al_h1b, en_h1w, en_h1b,
                                          al_bias, en_bias, act_b,
                                          hb1_b, hw2_b, hw1_b, hb2_w, hb2_b,
                                          wtAB, wt2, wtM, (float*)d_out);
}

// Round 14
// 34.808 us; speedup vs baseline: 1.1937x; 1.0439x over previous
//
#include <hip/hip_runtime.h>
#include <hip/hip_bf16.h>
#include <stdint.h>

typedef unsigned short u16t;
typedef float f32x4 __attribute__((ext_vector_type(4)));
typedef short bf16x8 __attribute__((ext_vector_type(8)));

#define SDIM 224

__device__ __forceinline__ float lo16(uint32_t w) { union { uint32_t u; float f; } v; v.u = w << 16; return v.f; }
__device__ __forceinline__ u16t bf1(float a) {
    union { __hip_bfloat16 h; u16t u; } c; c.h = __float2bfloat16(a); return c.u;
}
__device__ __forceinline__ uint32_t pk2(float a, float b) {
    union { __hip_bfloat162 h; uint32_t u; } c;
    c.h = __float22bfloat162_rn(make_float2(a, b));
    return c.u;
}

// ---------------------------------------------------------------------------
// Prep: pack GEMM B-operands, MFMA-frag order: buf[(kb*N+n)*8+j] = W[kb*8+j][n]
//  wtA: K=544: [0,512) h2wA (k=i*64+h), [512,520) h2bA rows, [520,544) zero
//  wtB: K=416: [0,384) h2wB, [384,390) h2bB, [390,404) act_w, [404,416) zero
//  wt2: K=64, N=64 (hb1_w | hw2_w);  wtM: K=64, N=32 (hw1_w)
// ---------------------------------------------------------------------------
__global__ void prep_wt_kernel(const float* __restrict__ h2wA, const float* __restrict__ h2wB,
                               const float* __restrict__ h2bA, const float* __restrict__ h2bB,
                               const float* __restrict__ actw,
                               const float* __restrict__ hb1w, const float* __restrict__ hw2w,
                               const float* __restrict__ hw1w,
                               u16t* __restrict__ wtA, u16t* __restrict__ wtB,
                               u16t* __restrict__ wt2, u16t* __restrict__ wtM)
{
    const int t0 = blockIdx.x * 256 + threadIdx.x, stride = gridDim.x * 256;
    for (int e = t0; e < 34816; e += stride) {
        int j = e & 7, n = (e >> 3) & 63, kb = e >> 9;
        int k = kb * 8 + j;
        float v = 0.f;
        if (k < 512)      { int h = k & 63, i = k >> 6; v = h2wA[h * 512 + i * 64 + n]; }
        else if (k < 520) v = h2bA[(k - 512) * 64 + n];
        wtA[e] = bf1(v);
    }
    for (int e = t0; e < 26624; e += stride) {
        int j = e & 7, n = (e >> 3) & 63, kb = e >> 9;
        int k = kb * 8 + j;
        float v = 0.f;
        if (k < 384)      { int h = k & 63, i = k >> 6; v = h2wB[h * 384 + i * 64 + n]; }
        else if (k < 390) v = h2bB[(k - 384) * 64 + n];
        else if (k < 404) v = actw[(k - 390) * 64 + n];
        wtB[e] = bf1(v);
    }
    for (int e = t0; e < 4096; e += stride) {
        int j = e & 7, n = (e >> 3) & 63, kb = e >> 9;
        int k = kb * 8 + j;
        float v = (n < 32) ? hb1w[k * 32 + n] : hw2w[k * 32 + (n - 32)];
        wt2[e] = bf1(v);
    }
    for (int e = t0; e < 2048; e += stride) {
        int j = e & 7, n = (e >> 3) & 31, kb = e >> 8;
        wtM[e] = bf1(hw1w[(kb * 8 + j) * 32 + n]);
    }
}

// ---------------------------------------------------------------------------
// stage1 from f32 x: psum[s][k=i*64+h] bf16, 4 samples/wave, lane = h.
// ---------------------------------------------------------------------------
template<int DIN, int KP, int FOFF>
__device__ __forceinline__ void stage1(const float (*sx)[112], u16t* __restrict__ ps,
                                       const float* __restrict__ s_h1w, float b1r,
                                       int wave, int lane)
{
    float w1r[DIN];
#pragma unroll
    for (int i = 0; i < DIN; ++i) w1r[i] = s_h1w[i * 64 + lane];
#pragma unroll 1
    for (int ss = 0; ss < 4; ++ss) {
        const int s = wave * 4 + ss;
        const float* xr = &sx[s][FOFF];
        float psv[DIN];
#pragma unroll
        for (int i = 0; i < DIN; ++i) psv[i] = 0.f;
#pragma unroll
        for (int a = 0; a < 8; ++a) {
            float x[DIN];
            if constexpr (DIN == 8) {
                float4 v0 = *(const float4*)(xr + a * 8);
                float4 v1 = *(const float4*)(xr + a * 8 + 4);
                x[0] = v0.x; x[1] = v0.y; x[2] = v0.z; x[3] = v0.w;
                x[4] = v1.x; x[5] = v1.y; x[6] = v1.z; x[7] = v1.w;
            } else {
                float2 v0 = *(const float2*)(xr + a * 6);
                float2 v1 = *(const float2*)(xr + a * 6 + 2);
                float2 v2 = *(const float2*)(xr + a * 6 + 4);
                x[0] = v0.x; x[1] = v0.y; x[2] = v1.x; x[3] = v1.y; x[4] = v2.x; x[5] = v2.y;
            }
            float hacc = b1r;
#pragma unroll
            for (int i = 0; i < DIN; ++i) hacc += x[i] * w1r[i];
            hacc = fmaxf(hacc, 0.f);
#pragma unroll
            for (int i = 0; i < DIN; ++i) psv[i] += hacc * x[i];
        }
#pragma unroll
        for (int i = 0; i < DIN; i += 2) {   // cvt_pk pair, split u16 writes
            union { __hip_bfloat162 h; struct { u16t lo, hi; } w; } c;
            c.h = __float22bfloat162_rn(make_float2(psv[i], psv[i + 1]));
            ps[s * KP + i * 64 + lane]       = c.w.lo;
            ps[s * KP + (i + 1) * 64 + lane] = c.w.hi;
        }
    }
}

// ---------------------------------------------------------------------------
// Fused mixer: 16 samples/block, grid 1024, 6 barriers (R10 structure),
// K-extended GEMMs, f32 x staging, cvt_pk packing.
// ---------------------------------------------------------------------------
__global__ __launch_bounds__(256, 4)
void fused_mixer(const float* __restrict__ qvals, const float* __restrict__ states,
                 const float* __restrict__ hs,
                 const float* __restrict__ al_h1w, const float* __restrict__ al_h1b,
                 const float* __restrict__ en_h1w, const float* __restrict__ en_h1b,
                 const float* __restrict__ al_bias, const float* __restrict__ en_bias,
                 const float* __restrict__ act_b,
                 const float* __restrict__ hb1_b, const float* __restrict__ hw2_b,
                 const float* __restrict__ hw1_b, const float* __restrict__ hb2_w,
                 const float* __restrict__ hb2_b,
                 const u16t* __restrict__ wtA, const u16t* __restrict__ wtB,
                 const u16t* __restrict__ wt2, const u16t* __restrict__ wtM,
                 float* __restrict__ out)
{
    constexpr int KPA = 552, KPB = 424;
    __shared__ __align__(16) char  s_un[18432];    // psumA(17664)/psumB(13568)/hs(18432)
    __shared__ __align__(16) float s_x[16][112];   // 7168 B f32 ally+enemy
    __shared__ float s_act[16][14];                // 896 B
    __shared__ __align__(16) u16t  s_se[16 * 72];  // 2304 B
    __shared__ float s_b1w2[16][64];               // 4096 B
    __shared__ float s_b2[16];
    __shared__ float s_q[128];
    __shared__ float s_h1wA[512], s_h1wB[384];
    __shared__ float s_h1bA[64], s_h1bB[64], s_bias3[64], s_hb2w[64];
    __shared__ float s_b1b[32], s_w2b[32], s_w1b[32];
    __shared__ float s_hb2bv;

    const int tid  = threadIdx.x;
    const int wave = tid >> 6;
    const int lane = tid & 63;
    const int lr = lane & 15, lg = lane >> 4;
    const int sbase = blockIdx.x * 16;
    const int o = wave * 16 + lr;                  // this thread's output column

    // ---- B0 staging ----
    for (int i = tid; i < 16 * 28; i += 256) {     // ally+enemy f32 copy (no cvt)
        int s = i / 28, c = i - s * 28;
        *(float4*)&s_x[s][c * 4] = *(const float4*)(states + (size_t)(sbase + s) * SDIM + c * 4);
    }
    if (tid < 224) {                               // action sums (raw, f32)
        int s = tid / 14, j = tid - s * 14;
        const float* ap = states + (size_t)(sbase + s) * SDIM + 112 + j;
        float t = 0.f;
#pragma unroll
        for (int a = 0; a < 8; ++a) t += ap[a * 14];
        s_act[s][j] = t;
    }
    for (int i = tid; i < 512; i += 256) s_h1wA[i] = al_h1w[i];
    for (int i = tid; i < 384; i += 256) s_h1wB[i] = en_h1w[i];
    if (tid < 64) {
        s_h1bA[tid] = al_h1b[tid]; s_h1bB[tid] = en_h1b[tid];
        s_bias3[tid] = al_bias[tid] + en_bias[tid] + act_b[tid];
        s_hb2w[tid] = hb2_w[tid];
    }
    if (tid >= 64 && tid < 96)   s_b1b[tid - 64] = hb1_b[tid - 64];
    if (tid >= 96 && tid < 128)  s_w2b[tid - 96] = hw2_b[tid - 96];
    if (tid >= 128 && tid < 160) s_w1b[tid - 128] = hw1_b[tid - 128];
    if (tid >= 160 && tid < 288 - 32) { /* spacing no-op */ }
    if (tid == 160) s_hb2bv = hb2_b[0];
    if (tid >= 128 && tid < 256 && tid - 128 < 128) s_q[tid - 128] = qvals[(size_t)sbase * 8 + (tid - 128)];
    __syncthreads();                               // B0

    u16t* ps = (u16t*)s_un;

    // ---- P1: stage1 A + xsumA rows + zero pad ----
    stage1<8, KPA, 0>(s_x, ps, s_h1wA, s_h1bA[lane], wave, lane);
    if (tid < 128) {                               // xsumA rows k=512..519
        int s = tid >> 3, i = tid & 7;
        float t = 0.f;
#pragma unroll
        for (int a = 0; a < 8; ++a) t += s_x[s][a * 8 + i];
        ps[s * KPA + 512 + i] = bf1(t);
    } else {                                       // zeros k=520..543 (12 u32 x 16)
        int idx = tid - 128;
        for (int u = idx; u < 192; u += 128) {
            int s = u / 12, r = u - s * 12;
            *(uint32_t*)&ps[s * KPA + 520 + r * 2] = 0u;
        }
    }
    __syncthreads();                               // B1

    // ---- P2: GEMM A, M=16, N=16/wave, K=544 ----
    f32x4 accA = {0.f, 0.f, 0.f, 0.f};
    {
        const u16t* arow = ps + lr * KPA + lg * 8;
        const bf16x8* wt8 = (const bf16x8*)wtA;
#pragma unroll 4
        for (int kk = 0; kk < 544; kk += 32) {
            bf16x8 av = *(const bf16x8*)(arow + kk);
            bf16x8 bv = wt8[((kk >> 3) + lg) * 64 + o];
            accA = __builtin_amdgcn_mfma_f32_16x16x32_bf16(av, bv, accA, 0, 0, 0);
        }
    }
    __syncthreads();                               // B2 (psumA free)

    // ---- P3: issue hs loads; stage1 B + ext rows ----
    float4 hsr[8];
    {
        const float4* hsv = (const float4*)(hs + (size_t)sbase * 512);
#pragma unroll
        for (int i = 0; i < 8; ++i) hsr[i] = hsv[i * 256 + tid];
    }
    stage1<6, KPB, 64>(s_x, ps, s_h1wB, s_h1bB[lane], wave, lane);
    if (tid < 96) {                                // xsumB rows k=384..389
        int s = tid / 6, i = tid - s * 6;
        float t = 0.f;
#pragma unroll
        for (int a = 0; a < 8; ++a) t += s_x[s][64 + a * 6 + i];
        ps[s * KPB + 384 + i] = bf1(t);
    } else {                                       // action rows k=390..403 (224)
        int idx = tid - 96;                        // 160 threads
        for (int u = idx; u < 224; u += 160) {
            int s = u / 14, j = u - s * 14;
            ps[s * KPB + 390 + j] = bf1(s_act[s][j]);
        }
    }
    if (tid < 96) {                                // zeros k=404..415 (6 u32 x 16)
        int s = tid / 6, r = tid - (tid / 6) * 6;
        *(uint32_t*)&ps[s * KPB + 404 + r * 2] = 0u;
    }
    __syncthreads();                               // B3

    // ---- P4: GEMM B K=416 + se epilogue ----
    {
        f32x4 accB = {0.f, 0.f, 0.f, 0.f};
        const u16t* arow = ps + lr * KPB + lg * 8;
        const bf16x8* wt8 = (const bf16x8*)wtB;
#pragma unroll 4
        for (int kk = 0; kk < 416; kk += 32) {
            bf16x8 av = *(const bf16x8*)(arow + kk);
            bf16x8 bv = wt8[((kk >> 3) + lg) * 64 + o];
            accB = __builtin_amdgcn_mfma_f32_16x16x32_bf16(av, bv, accB, 0, 0, 0);
        }
#pragma unroll
        for (int j = 0; j < 4; ++j) {              // D rows lg*4+j = samples 0..15
            const int row = lg * 4 + j;
            float se = (accA[j] + accB[j]) * 0.125f + s_bias3[o];
            s_se[row * 72 + o] = bf1(fmaxf(se, 0.f));
        }
    }
    __syncthreads();                               // B4 (se ready, psumB dead)

    // ---- P5: hs regs -> LDS | b1w2 MFMA | b2 reduce ----
    u16t* s_hs = (u16t*)s_un;
    {
#pragma unroll
        for (int i = 0; i < 8; ++i) {
            const int idx = i * 256 + tid;
            const int row = idx >> 4, c4 = idx & 15;
            uint2 p;
            p.x = pk2(hsr[i].x, hsr[i].y);
            p.y = pk2(hsr[i].z, hsr[i].w);
            *(uint2*)&s_hs[row * 72 + c4 * 4] = p;
        }
    }
    {   // b1w2: M=16, K=64, N=16/wave
        f32x4 acc = {0.f, 0.f, 0.f, 0.f};
        const u16t* serow = &s_se[lr * 72 + lg * 8];
        const bf16x8* wt8 = (const bf16x8*)wt2;
#pragma unroll
        for (int ks = 0; ks < 2; ++ks) {
            bf16x8 av = *(const bf16x8*)(serow + ks * 32);
            bf16x8 bv = wt8[(ks * 4 + lg) * 64 + o];
            acc = __builtin_amdgcn_mfma_f32_16x16x32_bf16(av, bv, acc, 0, 0, 0);
        }
#pragma unroll
        for (int j = 0; j < 4; ++j) {
            const int row = lg * 4 + j;
            float v = acc[j] + ((o < 32) ? s_b1b[o] : s_w2b[o - 32]);
            if (o >= 32) v = fabsf(v);
            s_b1w2[row][o] = v;
        }
    }
    {   // b2: group (wave,lg) reduces sample smp over 64 cols
        const int smp = wave * 4 + lg;
        float p = 0.f;
#pragma unroll
        for (int c = 0; c < 4; ++c) {
            const int oo = c * 16 + lr;
            p += lo16((uint32_t)s_se[smp * 72 + oo]) * s_hb2w[oo];
        }
        p += __shfl_xor(p, 1); p += __shfl_xor(p, 2);
        p += __shfl_xor(p, 4); p += __shfl_xor(p, 8);
        if (lr == 0) s_b2[smp] = p + s_hb2bv;
    }
    __syncthreads();                               // B5

    // ---- P6: mix (z MFMA, softmax over 8 agents, q-mix, ELU, final dot) ----
    bf16x8 bfr[2][2];
    {
        const bf16x8* wtm8 = (const bf16x8*)wtM;
#pragma unroll
        for (int n = 0; n < 2; ++n)
#pragma unroll
            for (int ks = 0; ks < 2; ++ks)
                bfr[n][ks] = wtm8[(ks * 4 + lg) * 32 + n * 16 + lr];
    }
    const float zb0 = s_w1b[lr], zb1 = s_w1b[16 + lr];

    for (int t = wave * 2; t < wave * 2 + 2; ++t) {
        f32x4 d0 = {0.f,0.f,0.f,0.f}, d1 = {0.f,0.f,0.f,0.f};
#pragma unroll
        for (int ks = 0; ks < 2; ++ks) {
            bf16x8 av = *(const bf16x8*)&s_hs[(t * 16 + lr) * 72 + ks * 32 + lg * 8];
            d0 = __builtin_amdgcn_mfma_f32_16x16x32_bf16(av, bfr[0][ks], d0, 0, 0, 0);
            d1 = __builtin_amdgcn_mfma_f32_16x16x32_bf16(av, bfr[1][ks], d1, 0, 0, 0);
        }
        const int sloc = t * 2 + (lg >> 1);
        float z0[4], z1[4];
#pragma unroll
        for (int j = 0; j < 4; ++j) { z0[j] = d0[j] + zb0; z1[j] = d1[j] + zb1; }
        float m0 = fmaxf(fmaxf(z0[0], z0[1]), fmaxf(z0[2], z0[3]));
        float m1 = fmaxf(fmaxf(z1[0], z1[1]), fmaxf(z1[2], z1[3]));
        m0 = fmaxf(m0, __shfl_xor(m0, 16));
        m1 = fmaxf(m1, __shfl_xor(m1, 16));
        float qa[4];
        {
            float4 qv = *(const float4*)&s_q[sloc * 8 + (lg & 1) * 4];
            qa[0] = qv.x; qa[1] = qv.y; qa[2] = qv.z; qa[3] = qv.w;
        }
        float s0 = 0.f, s1 = 0.f, hp0 = 0.f, hp1 = 0.f;
#pragma unroll
        for (int j = 0; j < 4; ++j) {
            float e0 = __expf(z0[j] - m0), e1 = __expf(z1[j] - m1);
            s0 += e0; s1 += e1;
            hp0 += qa[j] * e0; hp1 += qa[j] * e1;
        }
        s0  += __shfl_xor(s0, 16);  s1  += __shfl_xor(s1, 16);
        hp0 += __shfl_xor(hp0, 16); hp1 += __shfl_xor(hp1, 16);

        const float b1_0 = s_b1w2[sloc][lr],      b1_1 = s_b1w2[sloc][16 + lr];
        const float w2_0 = s_b1w2[sloc][32 + lr], w2_1 = s_b1w2[sloc][48 + lr];
        float h0 = hp0 / s0 + b1_0; h0 = (h0 > 0.f) ? h0 : (__expf(h0) - 1.f);
        float h1 = hp1 / s1 + b1_1; h1 = (h1 > 0.f) ? h1 : (__expf(h1) - 1.f);
        float yp = h0 * w2_0 + h1 * w2_1;
        yp += __shfl_xor(yp, 1); yp += __shfl_xor(yp, 2);
        yp += __shfl_xor(yp, 4); yp += __shfl_xor(yp, 8);
        if (lr == 0 && (lg & 1) == 0) out[sbase + sloc] = yp + s_b2[sloc];
    }
}

extern "C" void kernel_launch(void* const* d_in, const int* in_sizes, int n_in,
                              void* d_out, int out_size, void* d_ws, size_t ws_size,
                              hipStream_t stream) {
    const float* qvals   = (const float*)d_in[0];
    const float* states  = (const float*)d_in[1];
    const float* hstates = (const float*)d_in[2];
    const float* hw1_w   = (const float*)d_in[3];
    const float* hw1_b   = (const float*)d_in[4];
    const float* en_h1w  = (const float*)d_in[5];
    const float* en_h1b  = (const float*)d_in[6];
    const float* en_h2w  = (const float*)d_in[7];
    const float* en_h2b  = (const float*)d_in[8];
    const float* en_bias = (const float*)d_in[9];
    const float* al_h1w  = (const float*)d_in[10];
    const float* al_h1b  = (const float*)d_in[11];
    const float* al_h2w  = (const float*)d_in[12];
    const float* al_h2b  = (const float*)d_in[13];
    const float* al_bias = (const float*)d_in[14];
    const float* act_w   = (const float*)d_in[15];
    const float* act_b   = (const float*)d_in[16];
    const float* hb1_w   = (const float*)d_in[17];
    const float* hb1_b   = (const float*)d_in[18];
    const float* hw2_w   = (const float*)d_in[19];
    const float* hw2_b   = (const float*)d_in[20];
    const float* hb2_w   = (const float*)d_in[21];
    const float* hb2_b   = (const float*)d_in[22];

    // ws (u16): wtA@0 (34816) | wtB@34816 (26624) | wt2@61440 (4096) | wtM@65536 (2048)
    u16t* wtA = (u16t*)d_ws;
    u16t* wtB = wtA + 34816;
    u16t* wt2 = wtA + 61440;
    u16t* wtM = wtA + 65536;

    prep_wt_kernel<<<64, 256, 0, stream>>>(al_h2w, en_h2w, al_h2b, en_h2b, act_w,
                                           hb1_w, hw2_w, hw1_w, wtA, wtB, wt2, wtM);
    fused_mixer<<<1024, 256, 0, stream>>>(qvals, states, hstates,
                                          al_h1w, al_h1b, en_h1w, en_h1b,
                                          al_bias, en_bias, act_b,
                                          hb1_b, hw2_b, hw1_b, hb2_w, hb2_b,
                                          wtA, wtB, wt2, wtM, (float*)d_out);
}